// Round 1
// baseline (1217.732 us; speedup 1.0000x reference)
//
#include <hip/hip_runtime.h>

#define KK 27
#define CC 64
#define EPS 1e-5f

// ---------------------------------------------------------------------------
// Kernel 1: depthwise gather-conv + per-channel partial sum/sumsq
// Layout: block = 256 threads; cq = tid&15 (channel quad, 4 floats),
// rg = tid>>4 (row within the block's 16-row group). One wave covers 4 rows
// x 16 channel-quads -> each row's 256 B gather is 4 contiguous cachelines.
// ---------------------------------------------------------------------------
__global__ __launch_bounds__(256, 4) void conv_kernel(
    const float* __restrict__ data,     // [N][64]
    const float* __restrict__ weights,  // [27][64]
    const int*   __restrict__ neigh,    // [N][27]
    float* __restrict__ out,            // [N][64] conv output (temp, = d_out)
    float* __restrict__ gsum,           // [64] atomically accumulated
    float* __restrict__ gsq,            // [64]
    int N)
{
    __shared__ float4 s_w[KK * 16];     // weights as float4 [27][16]
    __shared__ float4 s_red[256];

    const int tid = threadIdx.x;
    for (int i = tid; i < KK * 16; i += 256)
        s_w[i] = reinterpret_cast<const float4*>(weights)[i];
    __syncthreads();

    const int cq = tid & 15;
    const int rg = tid >> 4;
    const float4* __restrict__ data4 = reinterpret_cast<const float4*>(data);
    float4* __restrict__ out4 = reinterpret_cast<float4*>(out);

    float4 lsum = {0.f, 0.f, 0.f, 0.f};
    float4 lsq  = {0.f, 0.f, 0.f, 0.f};

    const long rows_per_iter = (long)gridDim.x * 16;
    for (long base = (long)blockIdx.x * 16; base < N; base += rows_per_iter) {
        const long row = base + rg;
        if (row < N) {
            float4 acc = {0.f, 0.f, 0.f, 0.f};
            const int* __restrict__ nb = neigh + row * KK;
            #pragma unroll
            for (int k = 0; k < KK; ++k) {
                const int idx = nb[k];
                if (idx >= 0) {
                    const float4 g = data4[(long)idx * 16 + cq];
                    const float4 w = s_w[k * 16 + cq];
                    acc.x += g.x * w.x;
                    acc.y += g.y * w.y;
                    acc.z += g.z * w.z;
                    acc.w += g.w * w.w;
                }
            }
            out4[row * 16 + cq] = acc;
            lsum.x += acc.x; lsum.y += acc.y; lsum.z += acc.z; lsum.w += acc.w;
            lsq.x += acc.x * acc.x; lsq.y += acc.y * acc.y;
            lsq.z += acc.z * acc.z; lsq.w += acc.w * acc.w;
        }
    }

    // Block reduction across the 16 row-groups for each channel quad.
    s_red[tid] = lsum;
    __syncthreads();
    if (rg == 0) {
        float4 t = s_red[cq];
        #pragma unroll
        for (int r = 1; r < 16; ++r) {
            const float4 u = s_red[r * 16 + cq];
            t.x += u.x; t.y += u.y; t.z += u.z; t.w += u.w;
        }
        atomicAdd(&gsum[cq * 4 + 0], t.x);
        atomicAdd(&gsum[cq * 4 + 1], t.y);
        atomicAdd(&gsum[cq * 4 + 2], t.z);
        atomicAdd(&gsum[cq * 4 + 3], t.w);
    }
    __syncthreads();
    s_red[tid] = lsq;
    __syncthreads();
    if (rg == 0) {
        float4 t = s_red[cq];
        #pragma unroll
        for (int r = 1; r < 16; ++r) {
            const float4 u = s_red[r * 16 + cq];
            t.x += u.x; t.y += u.y; t.z += u.z; t.w += u.w;
        }
        atomicAdd(&gsq[cq * 4 + 0], t.x);
        atomicAdd(&gsq[cq * 4 + 1], t.y);
        atomicAdd(&gsq[cq * 4 + 2], t.z);
        atomicAdd(&gsq[cq * 4 + 3], t.w);
    }
}

// ---------------------------------------------------------------------------
// Kernel 2: fold sums into per-channel scale/bias
// ---------------------------------------------------------------------------
__global__ void stats_kernel(const float* __restrict__ gsum,
                             const float* __restrict__ gsq,
                             const float* __restrict__ gamma,
                             const float* __restrict__ beta,
                             float* __restrict__ scale,
                             float* __restrict__ bias,
                             int N)
{
    const int c = threadIdx.x;
    if (c < CC) {
        const float inv_n = 1.0f / (float)N;
        const float mean = gsum[c] * inv_n;
        float var = gsq[c] * inv_n - mean * mean;
        var = fmaxf(var, 0.0f);
        const float s = gamma[c] * rsqrtf(var + EPS);
        scale[c] = s;
        bias[c] = beta[c] - mean * s;
    }
}

// ---------------------------------------------------------------------------
// Kernel 3: in-place normalize out = out*scale[c] + bias[c], float4.
// stride = grid*256 is a multiple of 16 -> channel quad is loop-invariant.
// ---------------------------------------------------------------------------
__global__ __launch_bounds__(256, 8) void norm_kernel(
    float* __restrict__ out,
    const float* __restrict__ scale,
    const float* __restrict__ bias,
    long total4)
{
    const long i0 = (long)blockIdx.x * 256 + threadIdx.x;
    const int cq = (int)(i0 & 15);
    const float4 s = reinterpret_cast<const float4*>(scale)[cq];
    const float4 b = reinterpret_cast<const float4*>(bias)[cq];
    float4* __restrict__ o4 = reinterpret_cast<float4*>(out);
    const long stride = (long)gridDim.x * 256;   // multiple of 16
    for (long i = i0; i < total4; i += stride) {
        float4 v = o4[i];
        v.x = v.x * s.x + b.x;
        v.y = v.y * s.y + b.y;
        v.z = v.z * s.z + b.z;
        v.w = v.w * s.w + b.w;
        o4[i] = v;
    }
}

extern "C" void kernel_launch(void* const* d_in, const int* in_sizes, int n_in,
                              void* d_out, int out_size, void* d_ws, size_t ws_size,
                              hipStream_t stream)
{
    const float* data    = (const float*)d_in[0];
    const float* weights = (const float*)d_in[1];
    const float* gamma   = (const float*)d_in[2];
    const float* beta    = (const float*)d_in[3];
    const int*   neigh   = (const int*)d_in[4];
    float* out = (float*)d_out;
    const int N = in_sizes[0] / CC;     // 1,000,000

    float* gsum  = (float*)d_ws;        // [64]
    float* gsq   = gsum + CC;           // [64]
    float* scale = gsq + CC;            // [64]
    float* bias  = scale + CC;          // [64]

    // Zero the atomic accumulators (captured into the graph, so re-zeroed
    // on every replay).
    hipMemsetAsync(d_ws, 0, 2 * CC * sizeof(float), stream);

    conv_kernel<<<2048, 256, 0, stream>>>(data, weights, neigh, out, gsum, gsq, N);
    stats_kernel<<<1, 64, 0, stream>>>(gsum, gsq, gamma, beta, scale, bias, N);

    const long total4 = (long)N * (CC / 4);
    norm_kernel<<<2048, 256, 0, stream>>>(out, scale, bias, total4);
}

// Round 3
// 711.177 us; speedup vs baseline: 1.7123x; 1.7123x over previous
//
#include <hip/hip_runtime.h>

#define KK 27
#define CC 64
#define EPS 1e-5f

typedef float    f32x4 __attribute__((ext_vector_type(4)));
typedef unsigned u32x4 __attribute__((ext_vector_type(4)));

// ---------------------------------------------------------------------------
// Pack two fp32 -> bf16x2 (round-to-nearest-even)
// ---------------------------------------------------------------------------
__device__ __forceinline__ unsigned pack_bf16x2(float a, float b) {
    unsigned ua = __float_as_uint(a);
    unsigned ub = __float_as_uint(b);
    ua = (ua + 0x7fffu + ((ua >> 16) & 1u)) >> 16;
    ub = (ub + 0x7fffu + ((ub >> 16) & 1u)) >> 16;
    return ua | (ub << 16);
}

// ---------------------------------------------------------------------------
// Kernel 0: fp32 data [N][64] -> packed bf16 [N][64] (128 MB, L3-resident).
// NT read (stream once), normal write (populate caches).
// ---------------------------------------------------------------------------
__global__ __launch_bounds__(256, 8) void convert_kernel(
    const f32x4* __restrict__ d4, u32x4* __restrict__ o4, long n_out)
{
    const long stride = (long)gridDim.x * 256;
    for (long i = (long)blockIdx.x * 256 + threadIdx.x; i < n_out; i += stride) {
        f32x4 a = __builtin_nontemporal_load(&d4[2 * i]);
        f32x4 b = __builtin_nontemporal_load(&d4[2 * i + 1]);
        u32x4 o;
        o.x = pack_bf16x2(a.x, a.y);
        o.y = pack_bf16x2(a.z, a.w);
        o.z = pack_bf16x2(b.x, b.y);
        o.w = pack_bf16x2(b.z, b.w);
        o4[i] = o;
    }
}

// ---------------------------------------------------------------------------
// Kernel 1 (bf16 path): gather-conv + per-channel partial sums.
// 8 lanes per row (each lane: 8 channels as one u32x4 = 16B), 32 rows/block.
// Indices staged coalesced through LDS. Masked straightline loads (no branch)
// so the compiler can batch gathers for MLP. out written NT (don't evict L3).
// ---------------------------------------------------------------------------
__global__ __launch_bounds__(256, 4) void conv_bf16_kernel(
    const u32x4* __restrict__ dbf,      // [N][8] u32x4 rows (packed bf16)
    const float* __restrict__ weights,  // [27][64] fp32
    const int*   __restrict__ neigh,    // [N][27]
    float* __restrict__ out,            // [N][64] fp32
    float* __restrict__ gsum,
    float* __restrict__ gsq,
    int N)
{
    __shared__ float s_w[KK * CC];       // 6912 B
    __shared__ int   s_idx[32 * 28];     // 3584 B (row stride 28 -> 16B aligned)
    __shared__ float s_red[256 * 8];     // 8192 B

    const int tid = threadIdx.x;
    for (int i = tid; i < KK * CC / 4; i += 256)
        ((f32x4*)s_w)[i] = ((const f32x4*)weights)[i];

    const int lane = tid & 7;   // channel block: channels lane*8 .. lane*8+7
    const int r    = tid >> 3;  // row within block-iteration (0..31)

    float lsum[8], lsq[8];
    #pragma unroll
    for (int j = 0; j < 8; ++j) { lsum[j] = 0.f; lsq[j] = 0.f; }

    const long rows_per_iter = (long)gridDim.x * 32;
    for (long base = (long)blockIdx.x * 32; base < N; base += rows_per_iter) {
        __syncthreads();   // s_w ready (1st iter) / s_idx reads done (later)
        {
            const int nrows = (int)min((long)32, (long)N - base);
            const int tot = nrows * KK;
            for (int i = tid; i < tot; i += 256) {
                const int rr = i / KK;
                const int kk = i - rr * KK;
                s_idx[rr * 28 + kk] =
                    __builtin_nontemporal_load(&neigh[(base + rr) * KK + kk]);
            }
        }
        __syncthreads();

        const long row = base + r;
        if (row < N) {
            float acc[8];
            #pragma unroll
            for (int j = 0; j < 8; ++j) acc[j] = 0.f;

            const int4* nb4 = (const int4*)&s_idx[r * 28];

            auto process = [&](int idx, int k) {
                const unsigned msk = (idx >= 0) ? 0xffffffffu : 0u;
                const long ci = (idx >= 0) ? (long)idx : 0L;
                u32x4 g = dbf[ci * 8 + lane];
                g.x &= msk; g.y &= msk; g.z &= msk; g.w &= msk;
                const f32x4 w0 = *(const f32x4*)&s_w[k * CC + lane * 8];
                const f32x4 w1 = *(const f32x4*)&s_w[k * CC + lane * 8 + 4];
                acc[0] = fmaf(__uint_as_float(g.x << 16),         w0.x, acc[0]);
                acc[1] = fmaf(__uint_as_float(g.x & 0xffff0000u), w0.y, acc[1]);
                acc[2] = fmaf(__uint_as_float(g.y << 16),         w0.z, acc[2]);
                acc[3] = fmaf(__uint_as_float(g.y & 0xffff0000u), w0.w, acc[3]);
                acc[4] = fmaf(__uint_as_float(g.z << 16),         w1.x, acc[4]);
                acc[5] = fmaf(__uint_as_float(g.z & 0xffff0000u), w1.y, acc[5]);
                acc[6] = fmaf(__uint_as_float(g.w << 16),         w1.z, acc[6]);
                acc[7] = fmaf(__uint_as_float(g.w & 0xffff0000u), w1.w, acc[7]);
            };

            #pragma unroll
            for (int kk = 0; kk < 7; ++kk) {
                const int4 q = nb4[kk];
                const int kb = kk * 4;
                process(q.x, kb + 0);
                process(q.y, kb + 1);
                process(q.z, kb + 2);
                if (kb + 3 < KK) process(q.w, kb + 3);
            }

            f32x4 v0 = {acc[0], acc[1], acc[2], acc[3]};
            f32x4 v1 = {acc[4], acc[5], acc[6], acc[7]};
            f32x4* op = (f32x4*)&out[row * CC + lane * 8];
            __builtin_nontemporal_store(v0, &op[0]);
            __builtin_nontemporal_store(v1, &op[1]);

            #pragma unroll
            for (int j = 0; j < 8; ++j) {
                lsum[j] += acc[j];
                lsq[j]  += acc[j] * acc[j];
            }
        }
    }

    // Block reduction: channel c accumulated by threads with (tid&7)==c>>3.
    __syncthreads();
    #pragma unroll
    for (int j = 0; j < 8; ++j) s_red[tid * 8 + j] = lsum[j];
    __syncthreads();
    if (tid < CC) {
        const int blk = tid >> 3, off = tid & 7;
        float s = 0.f;
        for (int rr = 0; rr < 32; ++rr) s += s_red[(rr * 8 + blk) * 8 + off];
        atomicAdd(&gsum[tid], s);
    }
    __syncthreads();
    #pragma unroll
    for (int j = 0; j < 8; ++j) s_red[tid * 8 + j] = lsq[j];
    __syncthreads();
    if (tid < CC) {
        const int blk = tid >> 3, off = tid & 7;
        float s = 0.f;
        for (int rr = 0; rr < 32; ++rr) s += s_red[(rr * 8 + blk) * 8 + off];
        atomicAdd(&gsq[tid], s);
    }
}

// ---------------------------------------------------------------------------
// Fallback fp32 conv (used only if ws_size is too small for the bf16 copy).
// ---------------------------------------------------------------------------
__global__ __launch_bounds__(256, 4) void conv_fp32_kernel(
    const float* __restrict__ data,
    const float* __restrict__ weights,
    const int*   __restrict__ neigh,
    float* __restrict__ out,
    float* __restrict__ gsum,
    float* __restrict__ gsq,
    int N)
{
    __shared__ f32x4 s_w[KK * 16];
    __shared__ f32x4 s_red[256];

    const int tid = threadIdx.x;
    for (int i = tid; i < KK * 16; i += 256)
        s_w[i] = reinterpret_cast<const f32x4*>(weights)[i];
    __syncthreads();

    const int cq = tid & 15;
    const int rg = tid >> 4;
    const f32x4* data4 = reinterpret_cast<const f32x4*>(data);
    f32x4* out4 = reinterpret_cast<f32x4*>(out);

    f32x4 lsum = {0.f, 0.f, 0.f, 0.f};
    f32x4 lsq  = {0.f, 0.f, 0.f, 0.f};

    const long rows_per_iter = (long)gridDim.x * 16;
    for (long base = (long)blockIdx.x * 16; base < N; base += rows_per_iter) {
        const long row = base + rg;
        if (row < N) {
            f32x4 acc = {0.f, 0.f, 0.f, 0.f};
            const int* nb = neigh + row * KK;
            #pragma unroll
            for (int k = 0; k < KK; ++k) {
                const int idx = nb[k];
                if (idx >= 0) {
                    const f32x4 g = data4[(long)idx * 16 + cq];
                    const f32x4 w = s_w[k * 16 + cq];
                    acc += g * w;
                }
            }
            out4[row * 16 + cq] = acc;
            lsum += acc;
            lsq  += acc * acc;
        }
    }

    s_red[tid] = lsum;
    __syncthreads();
    if (rg == 0) {
        f32x4 t = s_red[cq];
        #pragma unroll
        for (int r = 1; r < 16; ++r) t += s_red[r * 16 + cq];
        atomicAdd(&gsum[cq * 4 + 0], t.x);
        atomicAdd(&gsum[cq * 4 + 1], t.y);
        atomicAdd(&gsum[cq * 4 + 2], t.z);
        atomicAdd(&gsum[cq * 4 + 3], t.w);
    }
    __syncthreads();
    s_red[tid] = lsq;
    __syncthreads();
    if (rg == 0) {
        f32x4 t = s_red[cq];
        #pragma unroll
        for (int r = 1; r < 16; ++r) t += s_red[r * 16 + cq];
        atomicAdd(&gsq[cq * 4 + 0], t.x);
        atomicAdd(&gsq[cq * 4 + 1], t.y);
        atomicAdd(&gsq[cq * 4 + 2], t.z);
        atomicAdd(&gsq[cq * 4 + 3], t.w);
    }
}

// ---------------------------------------------------------------------------
// Kernel 2: fold sums into per-channel scale/bias
// ---------------------------------------------------------------------------
__global__ void stats_kernel(const float* __restrict__ gsum,
                             const float* __restrict__ gsq,
                             const float* __restrict__ gamma,
                             const float* __restrict__ beta,
                             float* __restrict__ scale,
                             float* __restrict__ bias,
                             int N)
{
    const int c = threadIdx.x;
    if (c < CC) {
        const float inv_n = 1.0f / (float)N;
        const float mean = gsum[c] * inv_n;
        float var = gsq[c] * inv_n - mean * mean;
        var = fmaxf(var, 0.0f);
        const float s = gamma[c] * rsqrtf(var + EPS);
        scale[c] = s;
        bias[c] = beta[c] - mean * s;
    }
}

// ---------------------------------------------------------------------------
// Kernel 3: in-place normalize out = out*scale[c] + bias[c], f32x4, NT.
// ---------------------------------------------------------------------------
__global__ __launch_bounds__(256, 8) void norm_kernel(
    float* __restrict__ out,
    const float* __restrict__ scale,
    const float* __restrict__ bias,
    long total4)
{
    const long i0 = (long)blockIdx.x * 256 + threadIdx.x;
    const int cq = (int)(i0 & 15);
    const f32x4 s = reinterpret_cast<const f32x4*>(scale)[cq];
    const f32x4 b = reinterpret_cast<const f32x4*>(bias)[cq];
    f32x4* o4 = reinterpret_cast<f32x4*>(out);
    const long stride = (long)gridDim.x * 256;   // multiple of 16
    for (long i = i0; i < total4; i += stride) {
        f32x4 v = __builtin_nontemporal_load(&o4[i]);
        v = v * s + b;
        __builtin_nontemporal_store(v, &o4[i]);
    }
}

extern "C" void kernel_launch(void* const* d_in, const int* in_sizes, int n_in,
                              void* d_out, int out_size, void* d_ws, size_t ws_size,
                              hipStream_t stream)
{
    const float* data    = (const float*)d_in[0];
    const float* weights = (const float*)d_in[1];
    const float* gamma   = (const float*)d_in[2];
    const float* beta    = (const float*)d_in[3];
    const int*   neigh   = (const int*)d_in[4];
    float* out = (float*)d_out;
    const int N = in_sizes[0] / CC;     // 1,000,000

    float* gsum  = (float*)d_ws;        // [64]
    float* gsq   = gsum + CC;           // [64]
    float* scale = gsq + CC;            // [64]
    float* bias  = scale + CC;          // [64]

    (void)hipMemsetAsync(d_ws, 0, 2 * CC * sizeof(float), stream);

    const size_t bf16_bytes = (size_t)N * CC * 2;
    const size_t bf16_off = 1024;   // 16B-aligned, past the small arrays

    if (ws_size >= bf16_off + bf16_bytes) {
        u32x4* dbf = (u32x4*)((char*)d_ws + bf16_off);
        const long n_out = (long)N * CC / 8;   // u32x4 count
        convert_kernel<<<2048, 256, 0, stream>>>(
            (const f32x4*)data, dbf, n_out);
        conv_bf16_kernel<<<2048, 256, 0, stream>>>(
            (const u32x4*)dbf, weights, neigh, out, gsum, gsq, N);
    } else {
        conv_fp32_kernel<<<2048, 256, 0, stream>>>(
            data, weights, neigh, out, gsum, gsq, N);
    }

    stats_kernel<<<1, 64, 0, stream>>>(gsum, gsq, gamma, beta, scale, bias, N);

    const long total4 = (long)N * (CC / 4);
    norm_kernel<<<2048, 256, 0, stream>>>(out, scale, bias, total4);
}